// Round 13
// baseline (251.361 us; speedup 1.0000x reference)
//
#include <hip/hip_runtime.h>

#define TT 128
#define SS 512
#define NB 256
#define START_TAG 126
#define STOP_TAG 127
#define NEGV -10000.0f
#define LOG2E 1.4426950408889634f
#define LN2   0.6931471805599453f

typedef float v2 __attribute__((ext_vector_type(2)));
typedef __fp16 h2 __attribute__((ext_vector_type(2)));

__device__ __forceinline__ float ex2(float x) { return __builtin_amdgcn_exp2f(x); }         // 2^x
__device__ __forceinline__ float lg2(float x) { return __builtin_amdgcn_logf(x); }          // log2
__device__ __forceinline__ float exn(float x) { return __builtin_amdgcn_exp2f(x * LOG2E); } // e^x

__device__ __forceinline__ float rlane(float v, int lane) {
    return __int_as_float(__builtin_amdgcn_readlane(__float_as_int(v), lane));
}
__device__ __forceinline__ int rlane_i(int v, int lane) {
    return __builtin_amdgcn_readlane(v, lane);
}
// neighbor swap within pairs (lane ^ 1) via quad_perm(1,0,3,2)
__device__ __forceinline__ float swap1(float x) {
    int i = __float_as_int(x);
    int r = __builtin_amdgcn_update_dpp(i, i, 0xB1, 0xF, 0xF, true);
    return __int_as_float(r);
}
__device__ __forceinline__ int packp(float even, float odd_src) {
    h2 h = __builtin_amdgcn_cvt_pkrtz(even, odd_src);
    return __builtin_bit_cast(int, h);
}
__device__ __forceinline__ float wave_max(float v) {
#pragma unroll
    for (int off = 32; off >= 1; off >>= 1) v = fmaxf(v, __shfl_xor(v, off));
    return v;
}
__device__ __forceinline__ float wave_sum(float v) {
#pragma unroll
    for (int off = 32; off >= 1; off >>= 1) v += __shfl_xor(v, off);
    return v;
}

#define FOR32A(M) M(0) M(1) M(2) M(3) M(4) M(5) M(6) M(7) \
  M(8) M(9) M(10) M(11) M(12) M(13) M(14) M(15) \
  M(16) M(17) M(18) M(19) M(20) M(21) M(22) M(23) \
  M(24) M(25) M(26) M(27) M(28) M(29) M(30) M(31)
#define FOR32B(M) M(32) M(33) M(34) M(35) M(36) M(37) M(38) M(39) \
  M(40) M(41) M(42) M(43) M(44) M(45) M(46) M(47) \
  M(48) M(49) M(50) M(51) M(52) M(53) M(54) M(55) \
  M(56) M(57) M(58) M(59) M(60) M(61) M(62) M(63)
#define FOR64(M) FOR32A(M) FOR32B(M)

// One block per batch, 256 threads = 4 waves, each on its own SIMD.
//   wave 0: ENTIRE fwd chain (steps 0..255)   -- fully in-wave
//   wave 1: ENTIRE bwd chain (steps 511..256) -- fully in-wave
//   waves 2-3: gold-path score
// Z = LSE_j(A_256[j] + B_256[j]). Zero barriers / zero LDS in the step loop.
// E = packed f16 pairs over k (128 named h2 scalars). Dot = 64 immediate-lane
// readlanes + 128 v_dot2_f32_f16. Log2 domain (R9-validated recurrences).
// R13 change: step loop UNROLLED x8 with slot-renamed depth-8 feats pipeline.
// R12's rotating registers in a rolled loop forced s_waitcnt vmcnt(0) on a
// same-iteration HBM load (~400 cyc/step stall); with 8 bodies consuming
// slot j and refilling slot j for step s+j+8, the wait distance is a full
// unrolled block (>4000 cyc >> ~900 cyc HBM latency).
__global__ __launch_bounds__(256, 2) void crf_fwd_kernel(
    const float* __restrict__ feats,
    const float* __restrict__ trans,
    const int*   __restrict__ targets,
    float*       __restrict__ out)
{
    const int t = threadIdx.x;
    const int b = blockIdx.x;
    const int w = t >> 6;
    const int l = t & 63;

    __shared__ v2 bshare[64];
    __shared__ float redz[4];
    __shared__ float galpha;

    const size_t bst = (size_t)b * (SS * TT);
    float statex = 0.f, statey = 0.f;

    if (w < 2) {
        const int group = w;                    // 0 = fwd, 1 = bwd
        const float gsel = group ? 0.f : 1.f;   // fwd: emission folded post-log
        const float gnot = group ? 1.f : 0.f;   // bwd: emission folded into p-arg

#define DECL_E(i) h2 Ex##i, Ey##i;
        FOR64(DECL_E)
#undef DECL_E

        // fwd: Ex_i = {e^T[l][2i], e^T[l][2i+1]},  Ey_i: row l+64
        // bwd: Ex_i = {e^T[2i][l], e^T[2i+1][l]},  Ey_i: col l+64  (E^T)
        if (group == 0) {
            const float* r0 = trans + l * TT;
            const float* r1 = trans + (l + 64) * TT;
#define INIT_FWD(i) \
            Ex##i = __builtin_amdgcn_cvt_pkrtz(exn(r0[2*(i)]), exn(r0[2*(i)+1])); \
            Ey##i = __builtin_amdgcn_cvt_pkrtz(exn(r1[2*(i)]), exn(r1[2*(i)+1]));
            FOR64(INIT_FWD)
#undef INIT_FWD
        } else {
            const float* c0 = trans + l;
            const float* c1 = trans + l + 64;
#define INIT_BWD(i) \
            Ex##i = __builtin_amdgcn_cvt_pkrtz(exn(c0[(2*(i))*TT]), exn(c0[(2*(i)+1)*TT])); \
            Ey##i = __builtin_amdgcn_cvt_pkrtz(exn(c1[(2*(i))*TT]), exn(c1[(2*(i)+1)*TT]));
            FOR64(INIT_BWD)
#undef INIT_BWD
        }

        const float* fb = feats + bst + l;

        // depth-8 feats pipeline, slot j holds emission for step s+j
        // (log2-scaled). fwd index: step ; bwd index: 510 - step.
        float ffx[8], ffy[8];
#pragma unroll
        for (int j = 0; j < 8; ++j) {
            int idx = group ? (510 - j) : j;
            ffx[j] = fb[(size_t)idx * TT] * LOG2E;
            ffy[j] = fb[(size_t)idx * TT + 64] * LOG2E;
        }
        const int ii = group ? 511 : 0;
        float fInx = fb[(size_t)ii * TT] * LOG2E, fIny = fb[(size_t)ii * TT + 64] * LOG2E;

        // ---- init state (log2 domain) ----
        if (group == 0) {
            statex = NEGV;
            statey = (l == 62) ? 0.f : NEGV;        // START=126 = y-half lane 62
        } else {
            statex = trans[STOP_TAG * TT + l] * LOG2E;
            statey = trans[STOP_TAG * TT + l + 64] * LOG2E;
        }
        float agx = fmaf(fInx, gnot, statex);
        float agy = fmaf(fIny, gnot, statey);
        float M = group ? fmaxf(fmaxf(rlane(agx, 0), rlane(agy, 0)),
                                fmaxf(rlane(agx, 31), rlane(agy, 31)))
                        : 0.f;
        float px = ex2(agx - M);
        float py = ex2(agy - M);
        int ppkx = packp(px, swap1(px));   // even lane 2j holds (p_2j, p_2j+1)
        int ppky = packp(py, swap1(py));

        for (int s = 0; s < SS / 2; s += 8) {
#pragma unroll
            for (int j = 0; j < 8; ++j) {
                // ---- full 128-wide dot, in-wave ----
                float accx[4] = {0.f, 0.f, 0.f, 0.f};
                float accy[4] = {0.f, 0.f, 0.f, 0.f};
#define DOTA(i) { h2 pv = __builtin_bit_cast(h2, rlane_i(ppkx, 2*(i))); \
                accx[(i)&3] = __builtin_amdgcn_fdot2(pv, Ex##i, accx[(i)&3], false); \
                accy[(i)&3] = __builtin_amdgcn_fdot2(pv, Ey##i, accy[(i)&3], false); }
                FOR32A(DOTA)
#undef DOTA
#define DOTB(i) { h2 pv = __builtin_bit_cast(h2, rlane_i(ppky, 2*(i)-64)); \
                accx[(i)&3] = __builtin_amdgcn_fdot2(pv, Ex##i, accx[(i)&3], false); \
                accy[(i)&3] = __builtin_amdgcn_fdot2(pv, Ey##i, accy[(i)&3], false); }
                FOR32B(DOTB)
#undef DOTB
                float totx = (accx[0] + accx[1]) + (accx[2] + accx[3]);
                float toty = (accy[0] + accy[1]) + (accy[2] + accy[3]);

                // ---- combine + renormalize (log2 domain) ----
                statex = fmaf(ffx[j], gsel, lg2(totx) + M);
                statey = fmaf(ffy[j], gsel, lg2(toty) + M);
                agx = fmaf(ffx[j], gnot, statex);
                agy = fmaf(ffy[j], gnot, statey);
                M = fmaxf(fmaxf(rlane(agx, 0), rlane(agy, 0)),
                          fmaxf(rlane(agx, 31), rlane(agy, 31)));
                px = ex2(agx - M);
                py = ex2(agy - M);
                ppkx = packp(px, swap1(px));
                ppky = packp(py, swap1(py));

                // ---- refill slot j for step s+j+8 (consumed next block) ----
                // fwd: s+j+8 <= 263 < 512 (tail reads unused but in-bounds);
                // bwd: 510-(s+j+8) >= 247 >= 0.
                int sl = group ? (510 - (s + j + 8)) : (s + j + 8);
                ffx[j] = fb[(size_t)sl * TT] * LOG2E;
                ffy[j] = fb[(size_t)sl * TT + 64] * LOG2E;
            }
        }
        if (w == 1) bshare[l] = (v2){statex, statey};
    } else {
        // ---- gold path score on waves 2-3 (concurrent with chains) ----
        const int* tg = targets + b * SS;
        float gs = 0.f;
        for (int i = t - 128; i < SS; i += 128) {
            int cur  = tg[i];
            int prev = (i == 0) ? START_TAG : tg[i - 1];
            gs += trans[cur * TT + prev] + feats[bst + (size_t)i * TT + cur];
        }
        if (t == 128) gs += trans[STOP_TAG * TT + tg[SS - 1]];
        gs = wave_sum(gs);
        if (l == 0) redz[w] = gs;
    }
    __syncthreads();

    // ---- Z = LSE(A + B) on wave 0 (log2 domain) ----
    if (w == 0) {
        v2 bb = bshare[l];
        float vx = statex + bb.x;
        float vy = statey + bb.y;
        float m = wave_max(fmaxf(vx, vy));
        float e = ex2(vx - m) + ex2(vy - m);
        e = wave_sum(e);
        if (l == 0) galpha = (m + lg2(e)) * LN2;    // back to natural log
    }
    __syncthreads();

    if (t == 0) out[b] = (redz[2] + redz[3]) - galpha;
}

extern "C" void kernel_launch(void* const* d_in, const int* in_sizes, int n_in,
                              void* d_out, int out_size, void* d_ws, size_t ws_size,
                              hipStream_t stream) {
    const float* feats   = (const float*)d_in[0];
    const float* trans   = (const float*)d_in[1];
    const int*   targets = (const int*)d_in[2];
    float*       out     = (float*)d_out;
    crf_fwd_kernel<<<dim3(NB), dim3(256), 0, stream>>>(feats, trans, targets, out);
}